// Round 3
// baseline (841.922 us; speedup 1.0000x reference)
//
#include <hip/hip_runtime.h>
#include <hip/hip_bf16.h>
#include <math.h>

#define B_ 64
#define T_ 512
#define D_ 768
#define H_ 96
#define M_ (B_*T_)   // 32768 rows

// ---------------------------------------------------------------------------
// Kernel 1: fused QKV projection.  [M_,768] x [768,96] x3  -> q,k,v in d_ws.
// Block: 256 threads, 16 rows x 288 cols.  x-tile transposed in LDS so the
// inner loop reads 16 row-values with 4 broadcast ds_read_b128.  W streamed
// from global (884 KB total -> L2 resident), coalesced across lanes.
// ---------------------------------------------------------------------------
__global__ __launch_bounds__(256) void qkv_proj_kernel(
    const float* __restrict__ x,  const float* __restrict__ Wq,
    const float* __restrict__ Wk, const float* __restrict__ Wv,
    float* __restrict__ qp, float* __restrict__ kp, float* __restrict__ vp)
{
  __shared__ float xs[D_ * 16];          // transposed: xs[k][r], 48 KiB
  const int t    = threadIdx.x;
  const int row0 = blockIdx.x * 16;

  // stage x tile (16 rows x 768) transposed into LDS
  const float4* xg = reinterpret_cast<const float4*>(x) + (size_t)row0 * (D_/4);
  #pragma unroll
  for (int i = 0; i < 12; ++i) {
    int g  = t + i * 256;                // 0..3071 float4s
    int r  = g / (D_/4);
    int k4 = g % (D_/4);
    float4 f = xg[(size_t)r * (D_/4) + k4];
    xs[(k4*4 + 0)*16 + r] = f.x;
    xs[(k4*4 + 1)*16 + r] = f.y;
    xs[(k4*4 + 2)*16 + r] = f.z;
    xs[(k4*4 + 3)*16 + r] = f.w;
  }
  __syncthreads();

  // column assignment: thread t owns col t; threads 0..31 also own col 256+t
  const int  c1  = t;
  const int  m1  = c1 / 96;
  const int  cc1 = c1 % 96;
  const float* W1 = (m1 == 0) ? Wq : (m1 == 1 ? Wk : Wv);
  const bool has2 = (t < 32);
  const int  cc2  = t + 64;              // col 256+t -> matrix Wv, cc = t+64

  float acc1[16], acc2[16];
  #pragma unroll
  for (int r = 0; r < 16; ++r) { acc1[r] = 0.f; acc2[r] = 0.f; }

  #pragma unroll 4
  for (int k = 0; k < D_; ++k) {
    float w1 = W1[k*96 + cc1];
    const float4* xr = reinterpret_cast<const float4*>(&xs[k*16]);
    float4 a = xr[0], bq = xr[1], c = xr[2], d = xr[3];
    float xv[16] = {a.x,a.y,a.z,a.w, bq.x,bq.y,bq.z,bq.w,
                    c.x,c.y,c.z,c.w, d.x,d.y,d.z,d.w};
    #pragma unroll
    for (int r = 0; r < 16; ++r) acc1[r] = fmaf(xv[r], w1, acc1[r]);
    if (has2) {
      float w2 = Wv[k*96 + cc2];
      #pragma unroll
      for (int r = 0; r < 16; ++r) acc2[r] = fmaf(xv[r], w2, acc2[r]);
    }
  }

  float* o1 = (m1 == 0) ? qp : (m1 == 1 ? kp : vp);
  #pragma unroll
  for (int r = 0; r < 16; ++r)
    o1[(size_t)(row0 + r) * 96 + cc1] = acc1[r];
  if (has2) {
    #pragma unroll
    for (int r = 0; r < 16; ++r)
      vp[(size_t)(row0 + r) * 96 + cc2] = acc2[r];
  }
}

// ---------------------------------------------------------------------------
// Kernel 2: causal flash attention, fp32.
// Block: 256 threads = 32 q-rows x 8 col-groups (12 of 96 out dims each).
// K/V tiles of 32 keys staged in LDS (stride 100 floats: 16B-aligned +
// conflict-free).  Online softmax: per-row m/l replicated in registers over
// the 8-lane row group (consecutive lanes -> shfl_xor reductions).
// ---------------------------------------------------------------------------
__global__ __launch_bounds__(256) void attn_kernel(
    const float* __restrict__ qp, const float* __restrict__ kp,
    const float* __restrict__ vp, float* __restrict__ out)
{
  __shared__ float qs[32][100];
  __shared__ float ks[32][100];
  __shared__ float vs[32][100];
  __shared__ float sP[32][33];

  const int t  = threadIdx.x;
  const int qi = blockIdx.x;
  const int b  = blockIdx.y;
  const int q0 = qi * 32;
  const int r  = t >> 3;        // 0..31  q-row within tile
  const int jg = t & 7;         // 0..7   col-group / key-subgroup
  const int c0 = jg * 12;       // first out dim owned

  // stage q tile
  {
    const float* qbase = qp + (size_t)(b*T_ + q0) * 96;
    #pragma unroll
    for (int i = 0; i < 3; ++i) {
      int g = t + i*256;                 // 0..767 float4s
      int row = g / 24, col4 = g % 24;
      float4 f = *reinterpret_cast<const float4*>(qbase + (size_t)row*96 + col4*4);
      *reinterpret_cast<float4*>(&qs[row][col4*4]) = f;
    }
  }

  float acc[12];
  #pragma unroll
  for (int i = 0; i < 12; ++i) acc[i] = 0.f;
  float m_r = -INFINITY, l_r = 0.f;
  const float scale = 0.10206207261596576f;   // 1/sqrt(96)

  for (int j0 = 0; j0 <= q0; j0 += 32) {
    __syncthreads();   // previous PV done reading ks/vs (also covers q staging)
    {
      const float* kbase = kp + (size_t)(b*T_ + j0) * 96;
      const float* vbase = vp + (size_t)(b*T_ + j0) * 96;
      #pragma unroll
      for (int i = 0; i < 3; ++i) {
        int g = t + i*256;
        int row = g / 24, col4 = g % 24;
        *reinterpret_cast<float4*>(&ks[row][col4*4]) =
            *reinterpret_cast<const float4*>(kbase + (size_t)row*96 + col4*4);
        *reinterpret_cast<float4*>(&vs[row][col4*4]) =
            *reinterpret_cast<const float4*>(vbase + (size_t)row*96 + col4*4);
      }
    }
    __syncthreads();

    // scores: thread computes s[r][j] for j = jg, jg+8, jg+16, jg+24
    float sv[4] = {0.f, 0.f, 0.f, 0.f};
    #pragma unroll
    for (int h4 = 0; h4 < 24; ++h4) {
      float4 qv = *reinterpret_cast<const float4*>(&qs[r][h4*4]);
      #pragma unroll
      for (int jj = 0; jj < 4; ++jj) {
        float4 kv = *reinterpret_cast<const float4*>(&ks[jg + jj*8][h4*4]);
        sv[jj] = fmaf(qv.x, kv.x, sv[jj]);
        sv[jj] = fmaf(qv.y, kv.y, sv[jj]);
        sv[jj] = fmaf(qv.z, kv.z, sv[jj]);
        sv[jj] = fmaf(qv.w, kv.w, sv[jj]);
      }
    }
    #pragma unroll
    for (int jj = 0; jj < 4; ++jj) {
      int j = jg + jj*8;
      float s = sv[jj] * scale;
      if (j0 + j > q0 + r) s = -INFINITY;   // causal mask
      sv[jj] = s;
    }

    // row reduction over the 8 consecutive lanes of this row group
    float lm = fmaxf(fmaxf(sv[0], sv[1]), fmaxf(sv[2], sv[3]));
    #pragma unroll
    for (int o = 1; o < 8; o <<= 1) lm = fmaxf(lm, __shfl_xor(lm, o));
    float Mnew = fmaxf(m_r, lm);

    float psum = 0.f;
    #pragma unroll
    for (int jj = 0; jj < 4; ++jj) {
      float p = __expf(sv[jj] - Mnew);
      sP[r][jg + jj*8] = p;
      psum += p;
    }
    #pragma unroll
    for (int o = 1; o < 8; o <<= 1) psum += __shfl_xor(psum, o);

    float f = __expf(m_r - Mnew);   // first iter: exp(-inf)=0 cleans acc
    m_r = Mnew;
    l_r = l_r * f + psum;
    #pragma unroll
    for (int i = 0; i < 12; ++i) acc[i] *= f;

    __syncthreads();   // sP visible (same-wave anyway; cheap insurance)

    // PV: acc[i] += sum_j P[r][j] * v[j][c0+i]
    #pragma unroll 4
    for (int j = 0; j < 32; ++j) {
      float p = sP[r][j];
      const float* vrow = &vs[j][c0];
      float4 v0 = *reinterpret_cast<const float4*>(vrow);
      float4 v1 = *reinterpret_cast<const float4*>(vrow + 4);
      float4 v2 = *reinterpret_cast<const float4*>(vrow + 8);
      acc[0]  = fmaf(p, v0.x, acc[0]);  acc[1]  = fmaf(p, v0.y, acc[1]);
      acc[2]  = fmaf(p, v0.z, acc[2]);  acc[3]  = fmaf(p, v0.w, acc[3]);
      acc[4]  = fmaf(p, v1.x, acc[4]);  acc[5]  = fmaf(p, v1.y, acc[5]);
      acc[6]  = fmaf(p, v1.z, acc[6]);  acc[7]  = fmaf(p, v1.w, acc[7]);
      acc[8]  = fmaf(p, v2.x, acc[8]);  acc[9]  = fmaf(p, v2.y, acc[9]);
      acc[10] = fmaf(p, v2.z, acc[10]); acc[11] = fmaf(p, v2.w, acc[11]);
    }
  }

  const float inv = 1.f / l_r;
  float* obase = out + ((size_t)(b*T_ + q0 + r) * 96 + c0);
  float4 o0 = {acc[0]*inv,  acc[1]*inv,  acc[2]*inv,  acc[3]*inv};
  float4 o1 = {acc[4]*inv,  acc[5]*inv,  acc[6]*inv,  acc[7]*inv};
  float4 o2 = {acc[8]*inv,  acc[9]*inv,  acc[10]*inv, acc[11]*inv};
  *reinterpret_cast<float4*>(obase)     = o0;
  *reinterpret_cast<float4*>(obase + 4) = o1;
  *reinterpret_cast<float4*>(obase + 8) = o2;
}

extern "C" void kernel_launch(void* const* d_in, const int* in_sizes, int n_in,
                              void* d_out, int out_size, void* d_ws, size_t ws_size,
                              hipStream_t stream) {
  const float* x  = (const float*)d_in[0];
  const float* Wq = (const float*)d_in[1];
  const float* Wk = (const float*)d_in[2];
  const float* Wv = (const float*)d_in[3];
  float* qp = (float*)d_ws;                    // 3 x 32768 x 96 fp32 = 37.7 MB
  float* kp = qp + (size_t)M_ * H_;
  float* vp = kp + (size_t)M_ * H_;
  float* outp = (float*)d_out;

  hipLaunchKernelGGL(qkv_proj_kernel, dim3(M_/16), dim3(256), 0, stream,
                     x, Wq, Wk, Wv, qp, kp, vp);
  hipLaunchKernelGGL(attn_kernel, dim3(T_/32, B_), dim3(256), 0, stream,
                     qp, kp, vp, outp);
}

// Round 4
// 346.193 us; speedup vs baseline: 2.4319x; 2.4319x over previous
//
#include <hip/hip_runtime.h>
#include <hip/hip_bf16.h>
#include <math.h>

#define B_ 64
#define T_ 512
#define D_ 768
#define H_ 96
#define M_ (B_*T_)   // 32768 rows

#define BM 64
#define BK 16
#define ASTR 68      // padded stride for transposed A-tile (<=2-way on write, 0 on read)

// ---------------------------------------------------------------------------
// Kernel 1: QKV projection as register-blocked fp32 GEMM.
// Grid (512, 3): blockIdx.y selects Wq/Wk/Wv.  Block 256 = 16(tx, N) x 16(ty, M).
// Tile BM=64 x BN=96, BK=16 double-buffered.  Thread tile 4 rows x 6 cols:
// per k, 1 ds_read_b128 (A, broadcast) + 3 ds_read_b64 (B) feed 24 FMAs.
// ---------------------------------------------------------------------------
__global__ __launch_bounds__(256, 4) void qkv_proj_kernel(
    const float* __restrict__ x,  const float* __restrict__ Wq,
    const float* __restrict__ Wk, const float* __restrict__ Wv,
    float* __restrict__ qp, float* __restrict__ kp, float* __restrict__ vp)
{
  __shared__ float as[2][BK][ASTR];   // x-tile transposed [k][m], 2 x 4.25 KB
  __shared__ float bs[2][BK][H_];     // W-tile [k][n],          2 x 6 KB

  const int t    = threadIdx.x;
  const int row0 = blockIdx.x * BM;
  const int mi   = blockIdx.y;
  const float* Wm = (mi == 0) ? Wq : (mi == 1 ? Wk : Wv);
  float*       Om = (mi == 0) ? qp : (mi == 1 ? kp : vp);

  const int tx = t & 15;    // n-group: cols tx*6 .. tx*6+5
  const int ty = t >> 4;    // m-group: rows ty*4 .. ty*4+3

  const int ar  = t >> 2;   // 0..63  A-staging row
  const int ak4 = t & 3;    // 0..3   float4 index within BK

  float acc[4][6];
  #pragma unroll
  for (int i = 0; i < 4; ++i)
    #pragma unroll
    for (int j = 0; j < 6; ++j) acc[i][j] = 0.f;

  const float* xrow = x + (size_t)(row0 + ar) * D_ + ak4 * 4;

  // stage K-tile kt into LDS buffer buf
  auto stage = [&](int buf, int kt) {
    float4 a = *reinterpret_cast<const float4*>(xrow + kt);
    as[buf][ak4*4+0][ar] = a.x;     // bank = (16*ak4 + ar + 4c)%32 -> <=2-way
    as[buf][ak4*4+1][ar] = a.y;
    as[buf][ak4*4+2][ar] = a.z;
    as[buf][ak4*4+3][ar] = a.w;
    #pragma unroll
    for (int i = 0; i < 3; ++i) {
      int idx = t + i*256;          // 0..767 float2s of the 16x96 W tile
      int r = idx / 48, c2 = idx % 48;
      *reinterpret_cast<float2*>(&bs[buf][r][c2*2]) =
        *reinterpret_cast<const float2*>(&Wm[(size_t)(kt + r)*H_ + c2*2]);
    }
  };

  stage(0, 0);
  __syncthreads();

  for (int ks = 0; ks < D_/BK; ++ks) {
    int buf = ks & 1;
    if (ks + 1 < D_/BK) stage(buf^1, (ks+1)*BK);   // overlaps with compute below
    #pragma unroll
    for (int kk = 0; kk < BK; ++kk) {
      float4 av  = *reinterpret_cast<const float4*>(&as[buf][kk][ty*4]);
      float2 b01 = *reinterpret_cast<const float2*>(&bs[buf][kk][tx*6]);
      float2 b23 = *reinterpret_cast<const float2*>(&bs[buf][kk][tx*6+2]);
      float2 b45 = *reinterpret_cast<const float2*>(&bs[buf][kk][tx*6+4]);
      float avv[4] = {av.x, av.y, av.z, av.w};
      float bvv[6] = {b01.x, b01.y, b23.x, b23.y, b45.x, b45.y};
      #pragma unroll
      for (int i = 0; i < 4; ++i)
        #pragma unroll
        for (int j = 0; j < 6; ++j)
          acc[i][j] = fmaf(avv[i], bvv[j], acc[i][j]);
    }
    __syncthreads();
  }

  // epilogue: rows row0 + ty*4 + i, cols tx*6 + j
  #pragma unroll
  for (int i = 0; i < 4; ++i) {
    float* orow = Om + (size_t)(row0 + ty*4 + i) * H_ + tx*6;
    float2 o0 = {acc[i][0], acc[i][1]};
    float2 o1 = {acc[i][2], acc[i][3]};
    float2 o2 = {acc[i][4], acc[i][5]};
    *reinterpret_cast<float2*>(orow)     = o0;
    *reinterpret_cast<float2*>(orow + 2) = o1;
    *reinterpret_cast<float2*>(orow + 4) = o2;
  }
}

// ---------------------------------------------------------------------------
// Kernel 2: causal flash attention, fp32 (unchanged — ~21 us measured).
// ---------------------------------------------------------------------------
__global__ __launch_bounds__(256) void attn_kernel(
    const float* __restrict__ qp, const float* __restrict__ kp,
    const float* __restrict__ vp, float* __restrict__ out)
{
  __shared__ float qs[32][100];
  __shared__ float ks[32][100];
  __shared__ float vs[32][100];
  __shared__ float sP[32][33];

  const int t  = threadIdx.x;
  const int qi = blockIdx.x;
  const int b  = blockIdx.y;
  const int q0 = qi * 32;
  const int r  = t >> 3;        // 0..31  q-row within tile
  const int jg = t & 7;         // 0..7   col-group / key-subgroup
  const int c0 = jg * 12;       // first out dim owned

  {
    const float* qbase = qp + (size_t)(b*T_ + q0) * 96;
    #pragma unroll
    for (int i = 0; i < 3; ++i) {
      int g = t + i*256;
      int row = g / 24, col4 = g % 24;
      float4 f = *reinterpret_cast<const float4*>(qbase + (size_t)row*96 + col4*4);
      *reinterpret_cast<float4*>(&qs[row][col4*4]) = f;
    }
  }

  float acc[12];
  #pragma unroll
  for (int i = 0; i < 12; ++i) acc[i] = 0.f;
  float m_r = -INFINITY, l_r = 0.f;
  const float scale = 0.10206207261596576f;   // 1/sqrt(96)

  for (int j0 = 0; j0 <= q0; j0 += 32) {
    __syncthreads();
    {
      const float* kbase = kp + (size_t)(b*T_ + j0) * 96;
      const float* vbase = vp + (size_t)(b*T_ + j0) * 96;
      #pragma unroll
      for (int i = 0; i < 3; ++i) {
        int g = t + i*256;
        int row = g / 24, col4 = g % 24;
        *reinterpret_cast<float4*>(&ks[row][col4*4]) =
            *reinterpret_cast<const float4*>(kbase + (size_t)row*96 + col4*4);
        *reinterpret_cast<float4*>(&vs[row][col4*4]) =
            *reinterpret_cast<const float4*>(vbase + (size_t)row*96 + col4*4);
      }
    }
    __syncthreads();

    float sv[4] = {0.f, 0.f, 0.f, 0.f};
    #pragma unroll
    for (int h4 = 0; h4 < 24; ++h4) {
      float4 qv = *reinterpret_cast<const float4*>(&qs[r][h4*4]);
      #pragma unroll
      for (int jj = 0; jj < 4; ++jj) {
        float4 kv = *reinterpret_cast<const float4*>(&ks[jg + jj*8][h4*4]);
        sv[jj] = fmaf(qv.x, kv.x, sv[jj]);
        sv[jj] = fmaf(qv.y, kv.y, sv[jj]);
        sv[jj] = fmaf(qv.z, kv.z, sv[jj]);
        sv[jj] = fmaf(qv.w, kv.w, sv[jj]);
      }
    }
    #pragma unroll
    for (int jj = 0; jj < 4; ++jj) {
      int j = jg + jj*8;
      float s = sv[jj] * scale;
      if (j0 + j > q0 + r) s = -INFINITY;
      sv[jj] = s;
    }

    float lm = fmaxf(fmaxf(sv[0], sv[1]), fmaxf(sv[2], sv[3]));
    #pragma unroll
    for (int o = 1; o < 8; o <<= 1) lm = fmaxf(lm, __shfl_xor(lm, o));
    float Mnew = fmaxf(m_r, lm);

    float psum = 0.f;
    #pragma unroll
    for (int jj = 0; jj < 4; ++jj) {
      float p = __expf(sv[jj] - Mnew);
      sP[r][jg + jj*8] = p;
      psum += p;
    }
    #pragma unroll
    for (int o = 1; o < 8; o <<= 1) psum += __shfl_xor(psum, o);

    float f = __expf(m_r - Mnew);
    m_r = Mnew;
    l_r = l_r * f + psum;
    #pragma unroll
    for (int i = 0; i < 12; ++i) acc[i] *= f;

    __syncthreads();

    #pragma unroll 4
    for (int j = 0; j < 32; ++j) {
      float p = sP[r][j];
      const float* vrow = &vs[j][c0];
      float4 v0 = *reinterpret_cast<const float4*>(vrow);
      float4 v1 = *reinterpret_cast<const float4*>(vrow + 4);
      float4 v2 = *reinterpret_cast<const float4*>(vrow + 8);
      acc[0]  = fmaf(p, v0.x, acc[0]);  acc[1]  = fmaf(p, v0.y, acc[1]);
      acc[2]  = fmaf(p, v0.z, acc[2]);  acc[3]  = fmaf(p, v0.w, acc[3]);
      acc[4]  = fmaf(p, v1.x, acc[4]);  acc[5]  = fmaf(p, v1.y, acc[5]);
      acc[6]  = fmaf(p, v1.z, acc[6]);  acc[7]  = fmaf(p, v1.w, acc[7]);
      acc[8]  = fmaf(p, v2.x, acc[8]);  acc[9]  = fmaf(p, v2.y, acc[9]);
      acc[10] = fmaf(p, v2.z, acc[10]); acc[11] = fmaf(p, v2.w, acc[11]);
    }
  }

  const float inv = 1.f / l_r;
  float* obase = out + ((size_t)(b*T_ + q0 + r) * 96 + c0);
  float4 o0 = {acc[0]*inv,  acc[1]*inv,  acc[2]*inv,  acc[3]*inv};
  float4 o1 = {acc[4]*inv,  acc[5]*inv,  acc[6]*inv,  acc[7]*inv};
  float4 o2 = {acc[8]*inv,  acc[9]*inv,  acc[10]*inv, acc[11]*inv};
  *reinterpret_cast<float4*>(obase)     = o0;
  *reinterpret_cast<float4*>(obase + 4) = o1;
  *reinterpret_cast<float4*>(obase + 8) = o2;
}

extern "C" void kernel_launch(void* const* d_in, const int* in_sizes, int n_in,
                              void* d_out, int out_size, void* d_ws, size_t ws_size,
                              hipStream_t stream) {
  const float* x  = (const float*)d_in[0];
  const float* Wq = (const float*)d_in[1];
  const float* Wk = (const float*)d_in[2];
  const float* Wv = (const float*)d_in[3];
  float* qp = (float*)d_ws;                    // 3 x 32768 x 96 fp32 = 37.7 MB
  float* kp = qp + (size_t)M_ * H_;
  float* vp = kp + (size_t)M_ * H_;
  float* outp = (float*)d_out;

  hipLaunchKernelGGL(qkv_proj_kernel, dim3(M_/BM, 3), dim3(256), 0, stream,
                     x, Wq, Wk, Wv, qp, kp, vp);
  hipLaunchKernelGGL(attn_kernel, dim3(T_/32, B_), dim3(256), 0, stream,
                     qp, kp, vp, outp);
}

// Round 5
// 192.927 us; speedup vs baseline: 4.3639x; 1.7944x over previous
//
#include <hip/hip_runtime.h>
#include <hip/hip_bf16.h>
#include <math.h>

#define B_ 64
#define T_ 512
#define D_ 768
#define H_ 96
#define M_ (B_*T_)   // 32768 rows

typedef __attribute__((ext_vector_type(8))) short short8;
typedef __attribute__((ext_vector_type(4))) float f32x4;

__device__ __forceinline__ short f2bf(float f) {
  unsigned u = __float_as_uint(f);
  unsigned r = (u + 0x7FFFu + ((u >> 16) & 1u)) >> 16;   // RTNE
  return (short)r;
}

// ---------------------------------------------------------------------------
// Kernel 0: W -> bf16, transposed to [n][k] (n = mi*96+cc, 288 x 768).
// Lanes walk n -> coalesced fp32 reads; 2B scattered writes (442 KB, L2).
// ---------------------------------------------------------------------------
__global__ __launch_bounds__(256) void wt_kernel(
    const float* __restrict__ Wq, const float* __restrict__ Wk,
    const float* __restrict__ Wv, short* __restrict__ wt)
{
  int id = blockIdx.x * 256 + threadIdx.x;     // 3*96*768 = 221184
  if (id >= 3*H_*D_) return;
  int n = id % 288;
  int k = id / 288;
  int mi = n / 96, cc = n % 96;
  const float* Wm = (mi == 0) ? Wq : ((mi == 1) ? Wk : Wv);
  wt[(size_t)n * D_ + k] = f2bf(Wm[(size_t)k * H_ + cc]);
}

// ---------------------------------------------------------------------------
// Kernel 1: QKV projection via MFMA bf16 (fp32 accumulate).
// Grid 256 blocks (1/CU), block tile 128 rows x 288 cols (all 3 matrices ->
// x staged once).  4 waves in 2x2; wave tile 64x144 = 4x9 16x16 frags.
// BK=64 double-buffered; LDS stride 72 bf16 (144 B): frag reads 2-way (free),
// staging writes conflict-free.  A/B frag: lane l holds [idx&15][(l>>4)*8+j];
// C/D: col=lane&15, row=(lane>>4)*4+reg (m89-verified mapping).
// ---------------------------------------------------------------------------
#define BMP 128
#define BKP 64
#define ASTR 72

__global__ __launch_bounds__(256) void qkv_mfma_kernel(
    const float* __restrict__ x, const short* __restrict__ wt,
    float* __restrict__ qp, float* __restrict__ kp, float* __restrict__ vp)
{
  __shared__ short as[2][BMP][ASTR];   // 36,864 B
  __shared__ short bs[2][288][ASTR];   // 82,944 B   (total 119,808 B)

  const int t    = threadIdx.x;
  const int row0 = blockIdx.x * BMP;
  const int lane = t & 63;
  const int w    = t >> 6;
  const int wr   = w >> 1;      // row half (0..1)
  const int wc   = w & 1;       // col half (0..1)
  const int l15  = lane & 15;
  const int l4   = lane >> 4;   // 0..3  k-group

  auto stage = [&](int buf, int k0) {
    // x tile: 128 x 64 fp32 -> bf16.  1024 chunks of 8; 4 per thread.
    #pragma unroll
    for (int i = 0; i < 4; ++i) {
      int id = t + i * 256;
      int m = id >> 3, k8 = id & 7;
      const float* src = x + (size_t)(row0 + m) * D_ + k0 + k8 * 8;
      float4 f0 = *reinterpret_cast<const float4*>(src);
      float4 f1 = *reinterpret_cast<const float4*>(src + 4);
      short8 v;
      v[0] = f2bf(f0.x); v[1] = f2bf(f0.y); v[2] = f2bf(f0.z); v[3] = f2bf(f0.w);
      v[4] = f2bf(f1.x); v[5] = f2bf(f1.y); v[6] = f2bf(f1.z); v[7] = f2bf(f1.w);
      *reinterpret_cast<short8*>(&as[buf][m][k8 * 8]) = v;
    }
    // W tile: 288 x 64 bf16 (already transposed).  2304 chunks; 9 per thread.
    #pragma unroll
    for (int i = 0; i < 9; ++i) {
      int id = t + i * 256;
      int n = id >> 3, k8 = id & 7;
      short8 v = *reinterpret_cast<const short8*>(wt + (size_t)n * D_ + k0 + k8 * 8);
      *reinterpret_cast<short8*>(&bs[buf][n][k8 * 8]) = v;
    }
  };

  f32x4 acc[4][9];
  #pragma unroll
  for (int ri = 0; ri < 4; ++ri)
    #pragma unroll
    for (int ci = 0; ci < 9; ++ci) acc[ri][ci] = (f32x4){0.f, 0.f, 0.f, 0.f};

  stage(0, 0);
  __syncthreads();

  for (int ks = 0; ks < D_ / BKP; ++ks) {       // 12 steps
    int buf = ks & 1;
    if (ks + 1 < D_ / BKP) stage(buf ^ 1, (ks + 1) * BKP);

    #pragma unroll
    for (int kk = 0; kk < 2; ++kk) {            // two K=32 slices
      short8 a[4];
      #pragma unroll
      for (int ri = 0; ri < 4; ++ri) {
        int m = wr * 64 + ri * 16 + l15;
        a[ri] = *reinterpret_cast<const short8*>(&as[buf][m][kk * 32 + l4 * 8]);
      }
      #pragma unroll
      for (int ci = 0; ci < 9; ++ci) {
        int n = wc * 144 + ci * 16 + l15;
        short8 bfrag = *reinterpret_cast<const short8*>(&bs[buf][n][kk * 32 + l4 * 8]);
        #pragma unroll
        for (int ri = 0; ri < 4; ++ri)
          acc[ri][ci] = __builtin_amdgcn_mfma_f32_16x16x32_bf16(
              a[ri], bfrag, acc[ri][ci], 0, 0, 0);
      }
    }
    __syncthreads();
  }

  // epilogue: C frag (ri,ci): row = row0+wr*64+ri*16+(lane>>4)*4+reg,
  //                           col = wc*144+ci*16+(lane&15)
  #pragma unroll
  for (int ci = 0; ci < 9; ++ci) {
    int ncol = wc * 144 + ci * 16;
    int mi   = ncol / 96;
    int cc   = ncol % 96 + l15;
    float* Om = (mi == 0) ? qp : ((mi == 1) ? kp : vp);
    #pragma unroll
    for (int ri = 0; ri < 4; ++ri) {
      int rbase = row0 + wr * 64 + ri * 16 + l4 * 4;
      #pragma unroll
      for (int reg = 0; reg < 4; ++reg)
        Om[(size_t)(rbase + reg) * H_ + cc] = acc[ri][ci][reg];
    }
  }
}

// ---------------------------------------------------------------------------
// Kernel 2: causal flash attention, fp32 (unchanged).
// ---------------------------------------------------------------------------
__global__ __launch_bounds__(256) void attn_kernel(
    const float* __restrict__ qp, const float* __restrict__ kp,
    const float* __restrict__ vp, float* __restrict__ out)
{
  __shared__ float qs[32][100];
  __shared__ float ks[32][100];
  __shared__ float vs[32][100];
  __shared__ float sP[32][33];

  const int t  = threadIdx.x;
  const int qi = blockIdx.x;
  const int b  = blockIdx.y;
  const int q0 = qi * 32;
  const int r  = t >> 3;
  const int jg = t & 7;
  const int c0 = jg * 12;

  {
    const float* qbase = qp + (size_t)(b*T_ + q0) * 96;
    #pragma unroll
    for (int i = 0; i < 3; ++i) {
      int g = t + i*256;
      int row = g / 24, col4 = g % 24;
      float4 f = *reinterpret_cast<const float4*>(qbase + (size_t)row*96 + col4*4);
      *reinterpret_cast<float4*>(&qs[row][col4*4]) = f;
    }
  }

  float acc[12];
  #pragma unroll
  for (int i = 0; i < 12; ++i) acc[i] = 0.f;
  float m_r = -INFINITY, l_r = 0.f;
  const float scale = 0.10206207261596576f;   // 1/sqrt(96)

  for (int j0 = 0; j0 <= q0; j0 += 32) {
    __syncthreads();
    {
      const float* kbase = kp + (size_t)(b*T_ + j0) * 96;
      const float* vbase = vp + (size_t)(b*T_ + j0) * 96;
      #pragma unroll
      for (int i = 0; i < 3; ++i) {
        int g = t + i*256;
        int row = g / 24, col4 = g % 24;
        *reinterpret_cast<float4*>(&ks[row][col4*4]) =
            *reinterpret_cast<const float4*>(kbase + (size_t)row*96 + col4*4);
        *reinterpret_cast<float4*>(&vs[row][col4*4]) =
            *reinterpret_cast<const float4*>(vbase + (size_t)row*96 + col4*4);
      }
    }
    __syncthreads();

    float sv[4] = {0.f, 0.f, 0.f, 0.f};
    #pragma unroll
    for (int h4 = 0; h4 < 24; ++h4) {
      float4 qv = *reinterpret_cast<const float4*>(&qs[r][h4*4]);
      #pragma unroll
      for (int jj = 0; jj < 4; ++jj) {
        float4 kv = *reinterpret_cast<const float4*>(&ks[jg + jj*8][h4*4]);
        sv[jj] = fmaf(qv.x, kv.x, sv[jj]);
        sv[jj] = fmaf(qv.y, kv.y, sv[jj]);
        sv[jj] = fmaf(qv.z, kv.z, sv[jj]);
        sv[jj] = fmaf(qv.w, kv.w, sv[jj]);
      }
    }
    #pragma unroll
    for (int jj = 0; jj < 4; ++jj) {
      int j = jg + jj*8;
      float s = sv[jj] * scale;
      if (j0 + j > q0 + r) s = -INFINITY;
      sv[jj] = s;
    }

    float lm = fmaxf(fmaxf(sv[0], sv[1]), fmaxf(sv[2], sv[3]));
    #pragma unroll
    for (int o = 1; o < 8; o <<= 1) lm = fmaxf(lm, __shfl_xor(lm, o));
    float Mnew = fmaxf(m_r, lm);

    float psum = 0.f;
    #pragma unroll
    for (int jj = 0; jj < 4; ++jj) {
      float p = __expf(sv[jj] - Mnew);
      sP[r][jg + jj*8] = p;
      psum += p;
    }
    #pragma unroll
    for (int o = 1; o < 8; o <<= 1) psum += __shfl_xor(psum, o);

    float f = __expf(m_r - Mnew);
    m_r = Mnew;
    l_r = l_r * f + psum;
    #pragma unroll
    for (int i = 0; i < 12; ++i) acc[i] *= f;

    __syncthreads();

    #pragma unroll 4
    for (int j = 0; j < 32; ++j) {
      float p = sP[r][j];
      const float* vrow = &vs[j][c0];
      float4 v0 = *reinterpret_cast<const float4*>(vrow);
      float4 v1 = *reinterpret_cast<const float4*>(vrow + 4);
      float4 v2 = *reinterpret_cast<const float4*>(vrow + 8);
      acc[0]  = fmaf(p, v0.x, acc[0]);  acc[1]  = fmaf(p, v0.y, acc[1]);
      acc[2]  = fmaf(p, v0.z, acc[2]);  acc[3]  = fmaf(p, v0.w, acc[3]);
      acc[4]  = fmaf(p, v1.x, acc[4]);  acc[5]  = fmaf(p, v1.y, acc[5]);
      acc[6]  = fmaf(p, v1.z, acc[6]);  acc[7]  = fmaf(p, v1.w, acc[7]);
      acc[8]  = fmaf(p, v2.x, acc[8]);  acc[9]  = fmaf(p, v2.y, acc[9]);
      acc[10] = fmaf(p, v2.z, acc[10]); acc[11] = fmaf(p, v2.w, acc[11]);
    }
  }

  const float inv = 1.f / l_r;
  float* obase = out + ((size_t)(b*T_ + q0 + r) * 96 + c0);
  float4 o0 = {acc[0]*inv,  acc[1]*inv,  acc[2]*inv,  acc[3]*inv};
  float4 o1 = {acc[4]*inv,  acc[5]*inv,  acc[6]*inv,  acc[7]*inv};
  float4 o2 = {acc[8]*inv,  acc[9]*inv,  acc[10]*inv, acc[11]*inv};
  *reinterpret_cast<float4*>(obase)     = o0;
  *reinterpret_cast<float4*>(obase + 4) = o1;
  *reinterpret_cast<float4*>(obase + 8) = o2;
}

extern "C" void kernel_launch(void* const* d_in, const int* in_sizes, int n_in,
                              void* d_out, int out_size, void* d_ws, size_t ws_size,
                              hipStream_t stream) {
  const float* x  = (const float*)d_in[0];
  const float* Wq = (const float*)d_in[1];
  const float* Wk = (const float*)d_in[2];
  const float* Wv = (const float*)d_in[3];

  short* wt = (short*)d_ws;                              // 288*768*2 = 442,368 B
  float* qp = (float*)((char*)d_ws + 524288);            // 3 x 32768 x 96 fp32
  float* kp = qp + (size_t)M_ * H_;
  float* vp = kp + (size_t)M_ * H_;
  float* outp = (float*)d_out;

  hipLaunchKernelGGL(wt_kernel, dim3((3*H_*D_ + 255)/256), dim3(256), 0, stream,
                     Wq, Wk, Wv, wt);
  hipLaunchKernelGGL(qkv_mfma_kernel, dim3(M_/BMP), dim3(256), 0, stream,
                     x, wt, qp, kp, vp);
  hipLaunchKernelGGL(attn_kernel, dim3(T_/32, B_), dim3(256), 0, stream,
                     qp, kp, vp, outp);
}

// Round 6
// 81.985 us; speedup vs baseline: 10.2692x; 2.3532x over previous
//
#include <hip/hip_runtime.h>
#include <hip/hip_bf16.h>
#include <math.h>

#define B_ 64
#define T_ 512
#define D_ 768
#define H_ 96
#define M_ (B_*T_)   // 32768 rows

typedef __attribute__((ext_vector_type(8))) short short8;
typedef __attribute__((ext_vector_type(4))) float f32x4;

__device__ __forceinline__ short f2bf(float f) {
  unsigned u = __float_as_uint(f);
  unsigned r = (u + 0x7FFFu + ((u >> 16) & 1u)) >> 16;   // RTNE
  return (short)r;
}

// ---------------------------------------------------------------------------
// Kernel 0: W -> bf16, transposed to [n][k] (n = mi*96+cc, 288 x 768).
// ---------------------------------------------------------------------------
__global__ __launch_bounds__(256) void wt_kernel(
    const float* __restrict__ Wq, const float* __restrict__ Wk,
    const float* __restrict__ Wv, short* __restrict__ wt)
{
  int id = blockIdx.x * 256 + threadIdx.x;     // 3*96*768 = 221184
  if (id >= 3*H_*D_) return;
  int n = id % 288;
  int k = id / 288;
  int mi = n / 96, cc = n % 96;
  const float* Wm = (mi == 0) ? Wq : ((mi == 1) ? Wk : Wv);
  wt[(size_t)n * D_ + k] = f2bf(Wm[(size_t)k * H_ + cc]);
}

// ---------------------------------------------------------------------------
// Kernel 1: QKV projection via MFMA bf16 (fp32 accumulate), bf16 outputs.
// q,k: bf16 [M][96] row-major.  v: bf16 [B][96][T] (transposed per batch —
// C-frag rows are tokens, so each lane stores 4 consecutive tokens as 8B).
// ---------------------------------------------------------------------------
#define BMP 128
#define BKP 64
#define ASTR 72

__global__ __launch_bounds__(256) void qkv_mfma_kernel(
    const float* __restrict__ x, const short* __restrict__ wt,
    short* __restrict__ qb, short* __restrict__ kb, short* __restrict__ vtp)
{
  __shared__ short as[2][BMP][ASTR];   // 36,864 B
  __shared__ short bs[2][288][ASTR];   // 82,944 B

  const int t    = threadIdx.x;
  const int row0 = blockIdx.x * BMP;
  const int lane = t & 63;
  const int w    = t >> 6;
  const int wr   = w >> 1;
  const int wc   = w & 1;
  const int l15  = lane & 15;
  const int l4   = lane >> 4;

  auto stage = [&](int buf, int k0) {
    #pragma unroll
    for (int i = 0; i < 4; ++i) {
      int id = t + i * 256;
      int m = id >> 3, k8 = id & 7;
      const float* src = x + (size_t)(row0 + m) * D_ + k0 + k8 * 8;
      float4 f0 = *reinterpret_cast<const float4*>(src);
      float4 f1 = *reinterpret_cast<const float4*>(src + 4);
      short8 v;
      v[0] = f2bf(f0.x); v[1] = f2bf(f0.y); v[2] = f2bf(f0.z); v[3] = f2bf(f0.w);
      v[4] = f2bf(f1.x); v[5] = f2bf(f1.y); v[6] = f2bf(f1.z); v[7] = f2bf(f1.w);
      *reinterpret_cast<short8*>(&as[buf][m][k8 * 8]) = v;
    }
    #pragma unroll
    for (int i = 0; i < 9; ++i) {
      int id = t + i * 256;
      int n = id >> 3, k8 = id & 7;
      short8 v = *reinterpret_cast<const short8*>(wt + (size_t)n * D_ + k0 + k8 * 8);
      *reinterpret_cast<short8*>(&bs[buf][n][k8 * 8]) = v;
    }
  };

  f32x4 acc[4][9];
  #pragma unroll
  for (int ri = 0; ri < 4; ++ri)
    #pragma unroll
    for (int ci = 0; ci < 9; ++ci) acc[ri][ci] = (f32x4){0.f, 0.f, 0.f, 0.f};

  stage(0, 0);
  __syncthreads();

  for (int ks = 0; ks < D_ / BKP; ++ks) {
    int buf = ks & 1;
    if (ks + 1 < D_ / BKP) stage(buf ^ 1, (ks + 1) * BKP);
    #pragma unroll
    for (int kk = 0; kk < 2; ++kk) {
      short8 a[4];
      #pragma unroll
      for (int ri = 0; ri < 4; ++ri) {
        int m = wr * 64 + ri * 16 + l15;
        a[ri] = *reinterpret_cast<const short8*>(&as[buf][m][kk * 32 + l4 * 8]);
      }
      #pragma unroll
      for (int ci = 0; ci < 9; ++ci) {
        int n = wc * 144 + ci * 16 + l15;
        short8 bfrag = *reinterpret_cast<const short8*>(&bs[buf][n][kk * 32 + l4 * 8]);
        #pragma unroll
        for (int ri = 0; ri < 4; ++ri)
          acc[ri][ci] = __builtin_amdgcn_mfma_f32_16x16x32_bf16(
              a[ri], bfrag, acc[ri][ci], 0, 0, 0);
      }
    }
    __syncthreads();
  }

  // epilogue: C frag (ri,ci): row(token) = row0+wr*64+ri*16+l4*4+reg,
  //                           col(n)    = wc*144+ci*16+l15
  #pragma unroll
  for (int ci = 0; ci < 9; ++ci) {
    int ncol = wc * 144 + ci * 16;
    int mi   = ncol / 96;          // wave-uniform
    int cc   = ncol % 96 + l15;
    #pragma unroll
    for (int ri = 0; ri < 4; ++ri) {
      int rbase = row0 + wr * 64 + ri * 16 + l4 * 4;
      if (mi == 2) {
        int bb = rbase / T_, tl = rbase % T_;     // 4 tokens same batch (4 | T)
        short4 pk;
        pk.x = f2bf(acc[ri][ci][0]); pk.y = f2bf(acc[ri][ci][1]);
        pk.z = f2bf(acc[ri][ci][2]); pk.w = f2bf(acc[ri][ci][3]);
        *reinterpret_cast<short4*>(vtp + ((size_t)bb * H_ + cc) * T_ + tl) = pk;
      } else {
        short* Om = (mi == 0) ? qb : kb;
        #pragma unroll
        for (int reg = 0; reg < 4; ++reg)
          Om[(size_t)(rbase + reg) * H_ + cc] = f2bf(acc[ri][ci][reg]);
      }
    }
  }
}

// ---------------------------------------------------------------------------
// Kernel 2: causal flash attention via MFMA bf16.
// Block 128 thr = 2 waves; wave w owns q-rows [q0+w*16, +16).  KV tiles of 32.
// QK^T: both operands A-frag-style loads (row-major trick).  Online softmax
// per-lane on 4 C-rows; 16-lane shfl_xor reduces.  P -> bf16 via per-wave LDS
// re-fragment.  PV: A=P frag, B=V from pre-transposed vs[h][key].
// ---------------------------------------------------------------------------
#define QB 32
#define KVB 32
#define KSTR 104     // bf16; mult of 8 -> 16B-aligned rows; banks <=2-way
#define VSTR 40
#define PSTR 40

__global__ __launch_bounds__(128) void attn_mfma_kernel(
    const short* __restrict__ qb, const short* __restrict__ kb,
    const short* __restrict__ vtp, float* __restrict__ out)
{
  __shared__ short ks[KVB][KSTR];     // 6656 B
  __shared__ short vs[H_][VSTR];      // 7680 B
  __shared__ short ps[2][16][PSTR];   // 2560 B

  const int t    = threadIdx.x;
  const int lane = t & 63;
  const int w    = t >> 6;            // 0..1
  const int l15  = lane & 15;
  const int l4   = lane >> 4;
  const int qi   = 15 - blockIdx.x;   // heavy blocks first
  const int b    = blockIdx.y;
  const int q0   = qi * QB;

  // Q A-frags (3 h-slices), direct global loads
  short8 qf[3];
  {
    const short* qbase = qb + ((size_t)(b * T_) + q0 + w * 16 + l15) * H_;
    #pragma unroll
    for (int f = 0; f < 3; ++f)
      qf[f] = *reinterpret_cast<const short8*>(qbase + f * 32 + l4 * 8);
  }

  f32x4 acc[6];
  #pragma unroll
  for (int c = 0; c < 6; ++c) acc[c] = (f32x4){0.f, 0.f, 0.f, 0.f};
  float m_r[4] = {-INFINITY, -INFINITY, -INFINITY, -INFINITY};
  float l_r[4] = {0.f, 0.f, 0.f, 0.f};
  const float scale = 0.10206207261596576f;   // 1/sqrt(96)

  const int jmax = q0 + QB;
  for (int j0 = 0; j0 < jmax; j0 += KVB) {
    __syncthreads();   // prior tile's ks/vs reads done
    {  // stage K tile: 32 rows x 96 bf16
      int row = t >> 2, seg = t & 3;
      const short* src = kb + ((size_t)(b * T_) + j0 + row) * H_ + seg * 24;
      short* dst = &ks[row][seg * 24];
      *reinterpret_cast<short8*>(dst)      = *reinterpret_cast<const short8*>(src);
      *reinterpret_cast<short8*>(dst + 8)  = *reinterpret_cast<const short8*>(src + 8);
      *reinterpret_cast<short8*>(dst + 16) = *reinterpret_cast<const short8*>(src + 16);
    }
    {  // stage V tile: 96 h x 32 keys (already transposed in global)
      #pragma unroll
      for (int i = 0; i < 3; ++i) {
        int c = t + i * 128;
        int h = c >> 2, k8 = c & 3;
        *reinterpret_cast<short8*>(&vs[h][k8 * 8]) =
            *reinterpret_cast<const short8*>(vtp + ((size_t)b * H_ + h) * T_ + j0 + k8 * 8);
      }
    }
    __syncthreads();

    // QK^T: S[16 q x 32 j] as 2 col-tiles
    f32x4 sfr[2];
    sfr[0] = (f32x4){0.f,0.f,0.f,0.f};
    sfr[1] = (f32x4){0.f,0.f,0.f,0.f};
    #pragma unroll
    for (int ct = 0; ct < 2; ++ct)
      #pragma unroll
      for (int f = 0; f < 3; ++f) {
        short8 kf = *reinterpret_cast<const short8*>(&ks[ct * 16 + l15][f * 32 + l4 * 8]);
        sfr[ct] = __builtin_amdgcn_mfma_f32_16x16x32_bf16(qf[f], kf, sfr[ct], 0, 0, 0);
      }

    // online softmax on 4 rows (rr = l4*4+reg), cols l15 and l15+16
    const int qrow = q0 + w * 16 + l4 * 4;   // +reg
    float p0[4], p1[4], fsc[4];
    #pragma unroll
    for (int reg = 0; reg < 4; ++reg) {
      float s0 = sfr[0][reg] * scale;
      float s1 = sfr[1][reg] * scale;
      if (j0 + l15      > qrow + reg) s0 = -INFINITY;
      if (j0 + l15 + 16 > qrow + reg) s1 = -INFINITY;
      float tm = fmaxf(s0, s1);
      #pragma unroll
      for (int o = 1; o < 16; o <<= 1) tm = fmaxf(tm, __shfl_xor(tm, o));
      float Mnew = fmaxf(m_r[reg], tm);
      p0[reg] = __expf(s0 - Mnew);
      p1[reg] = __expf(s1 - Mnew);
      float psum = p0[reg] + p1[reg];
      #pragma unroll
      for (int o = 1; o < 16; o <<= 1) psum += __shfl_xor(psum, o);
      fsc[reg] = __expf(m_r[reg] - Mnew);
      m_r[reg] = Mnew;
      l_r[reg] = l_r[reg] * fsc[reg] + psum;
    }
    #pragma unroll
    for (int c = 0; c < 6; ++c)
      #pragma unroll
      for (int reg = 0; reg < 4; ++reg) acc[c][reg] *= fsc[reg];

    // P -> bf16 -> per-wave LDS re-fragment
    #pragma unroll
    for (int reg = 0; reg < 4; ++reg) {
      ps[w][l4 * 4 + reg][l15]      = f2bf(p0[reg]);
      ps[w][l4 * 4 + reg][l15 + 16] = f2bf(p1[reg]);
    }
    // same-wave LDS write->read: lgkmcnt ordering handled by compiler
    short8 pa = *reinterpret_cast<const short8*>(&ps[w][l15][l4 * 8]);

    // PV: D[16 q x 96 h] += P[16x32] * V[32x96]
    #pragma unroll
    for (int c = 0; c < 6; ++c) {
      short8 vf = *reinterpret_cast<const short8*>(&vs[c * 16 + l15][l4 * 8]);
      acc[c] = __builtin_amdgcn_mfma_f32_16x16x32_bf16(pa, vf, acc[c], 0, 0, 0);
    }
  }

  // epilogue
  float inv[4];
  #pragma unroll
  for (int reg = 0; reg < 4; ++reg) inv[reg] = 1.f / l_r[reg];
  #pragma unroll
  for (int c = 0; c < 6; ++c) {
    #pragma unroll
    for (int reg = 0; reg < 4; ++reg) {
      size_t row = (size_t)(b * T_) + q0 + w * 16 + l4 * 4 + reg;
      out[row * H_ + c * 16 + l15] = acc[c][reg] * inv[reg];
    }
  }
}

extern "C" void kernel_launch(void* const* d_in, const int* in_sizes, int n_in,
                              void* d_out, int out_size, void* d_ws, size_t ws_size,
                              hipStream_t stream) {
  const float* x  = (const float*)d_in[0];
  const float* Wq = (const float*)d_in[1];
  const float* Wk = (const float*)d_in[2];
  const float* Wv = (const float*)d_in[3];

  short* wt  = (short*)d_ws;                               // 442,368 B
  short* qb  = (short*)((char*)d_ws + 524288);             // 6,291,456 B
  short* kb  = qb + (size_t)M_ * H_;
  short* vtp = kb + (size_t)M_ * H_;                       // [B][96][T]
  float* outp = (float*)d_out;

  hipLaunchKernelGGL(wt_kernel, dim3((3*H_*D_ + 255)/256), dim3(256), 0, stream,
                     Wq, Wk, Wv, wt);
  hipLaunchKernelGGL(qkv_mfma_kernel, dim3(M_/BMP), dim3(256), 0, stream,
                     x, wt, qb, kb, vtp);
  hipLaunchKernelGGL(attn_mfma_kernel, dim3(T_/QB, B_), dim3(128), 0, stream,
                     qb, kb, vtp, outp);
}